// Round 5
// baseline (162.987 us; speedup 1.0000x reference)
//
#include <hip/hip_runtime.h>
#include <hip/hip_bf16.h>
#include <math.h>

typedef short short8 __attribute__((ext_vector_type(8)));
typedef float floatx4 __attribute__((ext_vector_type(4)));

#define NB 4096
#define DD 128
static constexpr float EPSF = 1e-8f;
static constexpr float TEMP = 11.313708498984760390f; // sqrt(128)

static __device__ __forceinline__ short f2bf(float f) {
    __hip_bfloat16 h = __float2bfloat16(f);
    union { __hip_bfloat16 h; short s; } u; u.h = h; return u.s;
}
static __device__ __forceinline__ float bf2f(short s) {
    union { __hip_bfloat16 h; short s; } u; u.s = s;
    return __bfloat162float(u.h);
}

// Pack 8 consecutive fp32 -> bf16x8 fragment
static __device__ __forceinline__ short8 load_cvt8(const float* __restrict__ p) {
    float4 a = *(const float4*)p;
    float4 b = *(const float4*)(p + 4);
    short8 o;
    o[0] = f2bf(a.x); o[1] = f2bf(a.y); o[2] = f2bf(a.z); o[3] = f2bf(a.w);
    o[4] = f2bf(b.x); o[5] = f2bf(b.y); o[6] = f2bf(b.z); o[7] = f2bf(b.w);
    return o;
}

// ---------------- projection + metric-normalize (MFMA, bf16) ----------------
// 256 blocks (one per CU): 32 rows x 128 cols each. 4 waves, each 32x32
// (2x2 tiles of 16x16x32). Also zeroes S (16 floats/block).
__global__ __launch_bounds__(256) void proj_kernel(
    const float* __restrict__ qp, const float* __restrict__ kp,
    const float* __restrict__ Wq, const float* __restrict__ bq,
    const float* __restrict__ Wk, const float* __restrict__ bk,
    __hip_bfloat16* __restrict__ qn, __hip_bfloat16* __restrict__ kn,
    float* __restrict__ rq, float* __restrict__ rk, float* __restrict__ S)
{
    int t = threadIdx.x;
    int b = blockIdx.x;                 // 0..255; 128 per matrix
    if (t < 16) S[b * 16 + t] = 0.0f;   // 256*16 = 4096

    int which = b >> 7;
    int row0 = (b & 127) * 32;
    const float* x    = which ? kp : qp;
    const float* W    = which ? Wk : Wq;
    const float* bias = which ? bk : bq;
    short* outv = which ? (short*)kn : (short*)qn;
    float* outr = which ? rk : rq;

    int lane = t & 63, wid = t >> 6;
    int m = lane & 15, quad = lane >> 4;
    int colb = wid * 32;                // wave col origin (4 waves x 32 cols)

    floatx4 acc[2][2];
    #pragma unroll
    for (int i = 0; i < 2; ++i)
        #pragma unroll
        for (int j = 0; j < 2; ++j)
            acc[i][j] = (floatx4){0.f, 0.f, 0.f, 0.f};

    #pragma unroll
    for (int ks = 0; ks < 4; ++ks) {
        int koff = ks * 32 + quad * 8;
        short8 af[2], bfr[2];
        #pragma unroll
        for (int rt = 0; rt < 2; ++rt)
            af[rt] = load_cvt8(x + (row0 + rt*16 + m) * DD + koff);
        #pragma unroll
        for (int ct = 0; ct < 2; ++ct)
            bfr[ct] = load_cvt8(W + (colb + ct*16 + m) * DD + koff);
        #pragma unroll
        for (int rt = 0; rt < 2; ++rt)
            #pragma unroll
            for (int ct = 0; ct < 2; ++ct)
                acc[rt][ct] = __builtin_amdgcn_mfma_f32_16x16x32_bf16(
                    af[rt], bfr[ct], acc[rt][ct], 0, 0, 0);
    }

    __shared__ float buf[4][32];
    __shared__ float nfb[32];

    float bv[2];
    #pragma unroll
    for (int ct = 0; ct < 2; ++ct) bv[ct] = bias[colb + ct*16 + m];

    // add bias; per-row sum of squares (this wave's 32 cols), reduce over m
    #pragma unroll
    for (int rt = 0; rt < 2; ++rt) {
        #pragma unroll
        for (int r = 0; r < 4; ++r) {
            float p = 0.0f;
            #pragma unroll
            for (int ct = 0; ct < 2; ++ct) {
                float v = acc[rt][ct][r] + bv[ct];
                acc[rt][ct][r] = v;
                p = fmaf(v, v, p);
            }
            p += __shfl_xor(p, 1); p += __shfl_xor(p, 2);
            p += __shfl_xor(p, 4); p += __shfl_xor(p, 8);
            if (m == 0) buf[wid][rt*16 + quad*4 + r] = p;
        }
    }
    __syncthreads();
    if (t < 32) {
        float s = buf[0][t] + buf[1][t] + buf[2][t] + buf[3][t];
        float fro = sqrtf(s*s*(1.0f/16384.0f) + s*(1.0f/64.0f) + 128.0f);
        float qnorm = sqrtf((s*s*(1.0f/128.0f) + s) / (fro + EPSF));
        nfb[t] = 1.0f / (qnorm + EPSF);
    }
    __syncthreads();

    // scale, round to bf16, store; row-sum of rounded squares
    #pragma unroll
    for (int rt = 0; rt < 2; ++rt) {
        #pragma unroll
        for (int r = 0; r < 4; ++r) {
            int lrow = rt*16 + quad*4 + r;      // block-local 0..31
            float nf = nfb[lrow];
            float u = 0.0f;
            #pragma unroll
            for (int ct = 0; ct < 2; ++ct) {
                float v = acc[rt][ct][r] * nf;
                short sb = f2bf(v);
                outv[(row0 + lrow) * DD + colb + ct*16 + m] = sb;
                float vf = bf2f(sb);
                u = fmaf(vf, vf, u);
            }
            u += __shfl_xor(u, 1); u += __shfl_xor(u, 2);
            u += __shfl_xor(u, 4); u += __shfl_xor(u, 8);
            if (m == 0) buf[wid][lrow] = u;
        }
    }
    __syncthreads();
    if (t < 32)
        outr[row0 + t] = buf[0][t] + buf[1][t] + buf[2][t] + buf[3][t];
}

// ---------------- single scores pass --------------------------------------
// Wave tile 32x32 (2x2 MFMA tiles, acc = 16 VGPRs) for high occupancy.
// Block = 2x2 waves = 64x64. Grid 64x64 = 4096 blocks.
// Computes e = exp(T/(1+dist)), stores UNNORMALIZED e to P (stays in LLC),
// atomicAdd row sums into S.
__global__ __launch_bounds__(256) void score_store(
    const __hip_bfloat16* __restrict__ qn, const __hip_bfloat16* __restrict__ kn,
    const float* __restrict__ rq, const float* __restrict__ rk,
    float* __restrict__ S, float* __restrict__ P)
{
    int lane = threadIdx.x & 63;
    int wid  = threadIdx.x >> 6;
    int m    = lane & 15;
    int quad = lane >> 4;

    int row0 = blockIdx.y * 64 + (wid >> 1) * 32;
    int col0 = blockIdx.x * 64 + (wid & 1) * 32;

    const short* qs  = (const short*)qn;
    const short* kks = (const short*)kn;

    floatx4 acc[2][2];
    #pragma unroll
    for (int i = 0; i < 2; ++i)
        #pragma unroll
        for (int j = 0; j < 2; ++j)
            acc[i][j] = (floatx4){0.f, 0.f, 0.f, 0.f};

    #pragma unroll
    for (int ks = 0; ks < 4; ++ks) {
        int koff = ks * 32 + quad * 8;
        short8 af[2], bfr[2];
        #pragma unroll
        for (int rt = 0; rt < 2; ++rt)
            af[rt] = *(const short8*)(qs + (row0 + rt*16 + m) * DD + koff);
        #pragma unroll
        for (int ct = 0; ct < 2; ++ct)
            bfr[ct] = *(const short8*)(kks + (col0 + ct*16 + m) * DD + koff);
        #pragma unroll
        for (int rt = 0; rt < 2; ++rt)
            #pragma unroll
            for (int ct = 0; ct < 2; ++ct)
                acc[rt][ct] = __builtin_amdgcn_mfma_f32_16x16x32_bf16(
                    af[rt], bfr[ct], acc[rt][ct], 0, 0, 0);
    }

    float rkv[2];
    #pragma unroll
    for (int ct = 0; ct < 2; ++ct) rkv[ct] = rk[col0 + ct*16 + m];

    #pragma unroll
    for (int rt = 0; rt < 2; ++rt) {
        #pragma unroll
        for (int r = 0; r < 4; ++r) {
            int row = row0 + rt*16 + quad*4 + r;
            float rqv = rq[row];
            float es = 0.0f;
            #pragma unroll
            for (int ct = 0; ct < 2; ++ct) {
                int col = col0 + ct*16 + m;
                float g  = acc[rt][ct][r];
                float d2 = fmaf(-2.0f, g, rqv + rkv[ct]);
                float d  = d2 > 0.0f ? __builtin_amdgcn_sqrtf(d2) : 0.0f;
                float e  = __expf(TEMP * __builtin_amdgcn_rcpf(1.0f + d));
                P[(long)row * NB + col] = e;     // unnormalized; lands in LLC
                es += e;
            }
            es += __shfl_xor(es, 1); es += __shfl_xor(es, 2);
            es += __shfl_xor(es, 4); es += __shfl_xor(es, 8);
            if (m == 0) atomicAdd(&S[row], es);
        }
    }
}

// ---------------- normalize: P /= S[row]  (LLC-resident read) --------------
__global__ __launch_bounds__(256) void norm_kernel(
    float* __restrict__ P, const float* __restrict__ S)
{
    long i = (long)blockIdx.x * 256 + threadIdx.x;   // float4 index
    int row = (int)(i >> 10);                        // 1024 float4 per row
    float inv = __builtin_amdgcn_rcpf(S[row] + EPSF);
    float4* P4 = (float4*)P;
    float4 v = P4[i];
    v.x *= inv; v.y *= inv; v.z *= inv; v.w *= inv;
    P4[i] = v;
}

extern "C" void kernel_launch(void* const* d_in, const int* in_sizes, int n_in,
                              void* d_out, int out_size, void* d_ws, size_t ws_size,
                              hipStream_t stream) {
    const float* qp = (const float*)d_in[0];
    const float* kp = (const float*)d_in[1];
    const float* Wq = (const float*)d_in[2];
    const float* bq = (const float*)d_in[3];
    const float* Wk = (const float*)d_in[4];
    const float* bk = (const float*)d_in[5];
    float* P = (float*)d_out;

    char* ws = (char*)d_ws;
    __hip_bfloat16* qn = (__hip_bfloat16*)ws;                         // 1 MB
    __hip_bfloat16* kn = (__hip_bfloat16*)(ws + (size_t)NB*DD*2);     // 1 MB
    float* rq = (float*)(ws + (size_t)NB*DD*4);                       // 16 KB
    float* rk = (float*)(ws + (size_t)NB*DD*4 + (size_t)NB*4);        // 16 KB
    float* S  = (float*)(ws + (size_t)NB*DD*4 + (size_t)2*NB*4);      // 16 KB

    hipLaunchKernelGGL(proj_kernel, dim3(256), dim3(256), 0, stream,
                       qp, kp, Wq, bq, Wk, bk, qn, kn, rq, rk, S);
    hipLaunchKernelGGL(score_store, dim3(64, 64), dim3(256), 0, stream,
                       qn, kn, rq, rk, S, P);
    hipLaunchKernelGGL(norm_kernel, dim3(16384), dim3(256), 0, stream, P, S);
}

// Round 6
// 133.209 us; speedup vs baseline: 1.2235x; 1.2235x over previous
//
#include <hip/hip_runtime.h>
#include <hip/hip_bf16.h>
#include <math.h>

typedef short short8 __attribute__((ext_vector_type(8)));
typedef float floatx4 __attribute__((ext_vector_type(4)));

#define NB 4096
#define DD 128
static constexpr float EPSF = 1e-8f;
static constexpr float TEMP = 11.313708498984760390f; // sqrt(128)

static __device__ __forceinline__ short f2bf(float f) {
    __hip_bfloat16 h = __float2bfloat16(f);
    union { __hip_bfloat16 h; short s; } u; u.h = h; return u.s;
}
static __device__ __forceinline__ float bf2f(short s) {
    union { __hip_bfloat16 h; short s; } u; u.s = s;
    return __bfloat162float(u.h);
}

// Pack 8 consecutive fp32 -> bf16x8 fragment
static __device__ __forceinline__ short8 load_cvt8(const float* __restrict__ p) {
    float4 a = *(const float4*)p;
    float4 b = *(const float4*)(p + 4);
    short8 o;
    o[0] = f2bf(a.x); o[1] = f2bf(a.y); o[2] = f2bf(a.z); o[3] = f2bf(a.w);
    o[4] = f2bf(b.x); o[5] = f2bf(b.y); o[6] = f2bf(b.z); o[7] = f2bf(b.w);
    return o;
}

// ---------------- projection + metric-normalize (MFMA, bf16) ----------------
// 256 blocks (one per CU): 32 rows x 128 cols each. 4 waves, each 32x32
// (2x2 tiles of 16x16x32).
__global__ __launch_bounds__(256) void proj_kernel(
    const float* __restrict__ qp, const float* __restrict__ kp,
    const float* __restrict__ Wq, const float* __restrict__ bq,
    const float* __restrict__ Wk, const float* __restrict__ bk,
    __hip_bfloat16* __restrict__ qn, __hip_bfloat16* __restrict__ kn,
    float* __restrict__ rq, float* __restrict__ rk)
{
    int t = threadIdx.x;
    int b = blockIdx.x;                 // 0..255; 128 per matrix

    int which = b >> 7;
    int row0 = (b & 127) * 32;
    const float* x    = which ? kp : qp;
    const float* W    = which ? Wk : Wq;
    const float* bias = which ? bk : bq;
    short* outv = which ? (short*)kn : (short*)qn;
    float* outr = which ? rk : rq;

    int lane = t & 63, wid = t >> 6;
    int m = lane & 15, quad = lane >> 4;
    int colb = wid * 32;                // wave col origin (4 waves x 32 cols)

    floatx4 acc[2][2];
    #pragma unroll
    for (int i = 0; i < 2; ++i)
        #pragma unroll
        for (int j = 0; j < 2; ++j)
            acc[i][j] = (floatx4){0.f, 0.f, 0.f, 0.f};

    #pragma unroll
    for (int ks = 0; ks < 4; ++ks) {
        int koff = ks * 32 + quad * 8;
        short8 af[2], bfr[2];
        #pragma unroll
        for (int rt = 0; rt < 2; ++rt)
            af[rt] = load_cvt8(x + (row0 + rt*16 + m) * DD + koff);
        #pragma unroll
        for (int ct = 0; ct < 2; ++ct)
            bfr[ct] = load_cvt8(W + (colb + ct*16 + m) * DD + koff);
        #pragma unroll
        for (int rt = 0; rt < 2; ++rt)
            #pragma unroll
            for (int ct = 0; ct < 2; ++ct)
                acc[rt][ct] = __builtin_amdgcn_mfma_f32_16x16x32_bf16(
                    af[rt], bfr[ct], acc[rt][ct], 0, 0, 0);
    }

    __shared__ float buf[4][32];
    __shared__ float nfb[32];

    float bv[2];
    #pragma unroll
    for (int ct = 0; ct < 2; ++ct) bv[ct] = bias[colb + ct*16 + m];

    // add bias; per-row sum of squares (this wave's 32 cols), reduce over m
    #pragma unroll
    for (int rt = 0; rt < 2; ++rt) {
        #pragma unroll
        for (int r = 0; r < 4; ++r) {
            float p = 0.0f;
            #pragma unroll
            for (int ct = 0; ct < 2; ++ct) {
                float v = acc[rt][ct][r] + bv[ct];
                acc[rt][ct][r] = v;
                p = fmaf(v, v, p);
            }
            p += __shfl_xor(p, 1); p += __shfl_xor(p, 2);
            p += __shfl_xor(p, 4); p += __shfl_xor(p, 8);
            if (m == 0) buf[wid][rt*16 + quad*4 + r] = p;
        }
    }
    __syncthreads();
    if (t < 32) {
        float s = buf[0][t] + buf[1][t] + buf[2][t] + buf[3][t];
        float fro = sqrtf(s*s*(1.0f/16384.0f) + s*(1.0f/64.0f) + 128.0f);
        float qnorm = sqrtf((s*s*(1.0f/128.0f) + s) / (fro + EPSF));
        nfb[t] = 1.0f / (qnorm + EPSF);
    }
    __syncthreads();

    // scale, round to bf16, store; row-sum of rounded squares
    #pragma unroll
    for (int rt = 0; rt < 2; ++rt) {
        #pragma unroll
        for (int r = 0; r < 4; ++r) {
            int lrow = rt*16 + quad*4 + r;      // block-local 0..31
            float nf = nfb[lrow];
            float u = 0.0f;
            #pragma unroll
            for (int ct = 0; ct < 2; ++ct) {
                float v = acc[rt][ct][r] * nf;
                short sb = f2bf(v);
                outv[(row0 + lrow) * DD + colb + ct*16 + m] = sb;
                float vf = bf2f(sb);
                u = fmaf(vf, vf, u);
            }
            u += __shfl_xor(u, 1); u += __shfl_xor(u, 2);
            u += __shfl_xor(u, 4); u += __shfl_xor(u, 8);
            if (m == 0) buf[wid][lrow] = u;
        }
    }
    __syncthreads();
    if (t < 32)
        outr[row0 + t] = buf[0][t] + buf[1][t] + buf[2][t] + buf[3][t];
}

// ---------------- scores: block owns 16 FULL rows ---------------------------
// 256 blocks x 512 threads. Wave w owns cols [w*512, w*512+512).
// Phase A: loop 8 x 64-col tiles; GEMM 16x64 (K=128), epilogue e kept in acc
//          regs (128 fp32/lane); row sums accumulate in registers.
// LDS reduce across 8 waves -> inv = 1/(S+EPS) (block-local; no atomics).
// Phase B: store P = e * inv, addresses ascending sequentially per row
//          (2 KB runs per wave per row -> DRAM-friendly streaming writes).
__global__ __launch_bounds__(512) void score_rows(
    const __hip_bfloat16* __restrict__ qn, const __hip_bfloat16* __restrict__ kn,
    const float* __restrict__ rq, const float* __restrict__ rk,
    float* __restrict__ P)
{
    int lane = threadIdx.x & 63;
    int wid  = threadIdx.x >> 6;        // 0..7
    int m    = lane & 15;
    int quad = lane >> 4;

    int r0 = blockIdx.x * 16;           // 16 rows per block
    int cs = wid * 512;                 // wave's column strip

    const short* qs  = (const short*)qn;
    const short* kks = (const short*)kn;

    // A fragments: 16 rows x K=128, held across all iterations (16 VGPRs)
    short8 af[4];
    #pragma unroll
    for (int k = 0; k < 4; ++k)
        af[k] = *(const short8*)(qs + (r0 + m) * DD + k*32 + quad*8);

    float rqv[4];
    #pragma unroll
    for (int r = 0; r < 4; ++r) rqv[r] = rq[r0 + quad*4 + r];

    floatx4 acc[8][4];                  // e values: 16 rows x 512 cols / 64 lanes
    float rs[4] = {0.f, 0.f, 0.f, 0.f}; // running row sums (rows quad*4+r)

    #pragma unroll
    for (int it = 0; it < 8; ++it) {
        int cb = cs + it * 64;
        #pragma unroll
        for (int ct = 0; ct < 4; ++ct) {
            int col = cb + ct*16 + m;
            short8 bfr[4];
            #pragma unroll
            for (int k = 0; k < 4; ++k)
                bfr[k] = *(const short8*)(kks + col * DD + k*32 + quad*8);
            floatx4 a = (floatx4){0.f, 0.f, 0.f, 0.f};
            #pragma unroll
            for (int k = 0; k < 4; ++k)
                a = __builtin_amdgcn_mfma_f32_16x16x32_bf16(af[k], bfr[k], a, 0, 0, 0);
            float rkv = rk[col];
            #pragma unroll
            for (int r = 0; r < 4; ++r) {
                float d2 = fmaf(-2.0f, a[r], rqv[r] + rkv);
                float d  = d2 > 0.0f ? __builtin_amdgcn_sqrtf(d2) : 0.0f;
                float e  = __expf(TEMP * __builtin_amdgcn_rcpf(1.0f + d));
                a[r] = e;
                rs[r] += e;
            }
            acc[it][ct] = a;
        }
    }

    // reduce row sums over the 16 m-lanes (stays within each quad group)
    #pragma unroll
    for (int r = 0; r < 4; ++r) {
        rs[r] += __shfl_xor(rs[r], 1); rs[r] += __shfl_xor(rs[r], 2);
        rs[r] += __shfl_xor(rs[r], 4); rs[r] += __shfl_xor(rs[r], 8);
    }

    __shared__ float sums[8][16];
    __shared__ float inv[16];
    if (m == 0) {
        #pragma unroll
        for (int r = 0; r < 4; ++r) sums[wid][quad*4 + r] = rs[r];
    }
    __syncthreads();
    if (threadIdx.x < 16) {
        float s = 0.f;
        #pragma unroll
        for (int w = 0; w < 8; ++w) s += sums[w][threadIdx.x];
        inv[threadIdx.x] = __builtin_amdgcn_rcpf(s + EPSF);
    }
    __syncthreads();

    float invv[4];
    #pragma unroll
    for (int r = 0; r < 4; ++r) invv[r] = inv[quad*4 + r];

    // Phase B: single normalized store, sequential addresses per row
    #pragma unroll
    for (int it = 0; it < 8; ++it) {
        int cb = cs + it * 64;
        #pragma unroll
        for (int ct = 0; ct < 4; ++ct) {
            #pragma unroll
            for (int r = 0; r < 4; ++r) {
                long row = r0 + quad*4 + r;
                P[row * NB + cb + ct*16 + m] = acc[it][ct][r] * invv[r];
            }
        }
    }
}

extern "C" void kernel_launch(void* const* d_in, const int* in_sizes, int n_in,
                              void* d_out, int out_size, void* d_ws, size_t ws_size,
                              hipStream_t stream) {
    const float* qp = (const float*)d_in[0];
    const float* kp = (const float*)d_in[1];
    const float* Wq = (const float*)d_in[2];
    const float* bq = (const float*)d_in[3];
    const float* Wk = (const float*)d_in[4];
    const float* bk = (const float*)d_in[5];
    float* P = (float*)d_out;

    char* ws = (char*)d_ws;
    __hip_bfloat16* qn = (__hip_bfloat16*)ws;                         // 1 MB
    __hip_bfloat16* kn = (__hip_bfloat16*)(ws + (size_t)NB*DD*2);     // 1 MB
    float* rq = (float*)(ws + (size_t)NB*DD*4);                       // 16 KB
    float* rk = (float*)(ws + (size_t)NB*DD*4 + (size_t)NB*4);        // 16 KB

    hipLaunchKernelGGL(proj_kernel, dim3(256), dim3(256), 0, stream,
                       qp, kp, Wq, bq, Wk, bk, qn, kn, rq, rk);
    hipLaunchKernelGGL(score_rows, dim3(256), dim3(512), 0, stream,
                       qn, kn, rq, rk, P);
}

// Round 7
// 117.044 us; speedup vs baseline: 1.3925x; 1.1381x over previous
//
#include <hip/hip_runtime.h>
#include <hip/hip_bf16.h>
#include <math.h>

typedef short short8 __attribute__((ext_vector_type(8)));
typedef float floatx4 __attribute__((ext_vector_type(4)));

#define NB 4096
#define DD 128
static constexpr float EPSF = 1e-8f;
static constexpr float TEMP = 11.313708498984760390f; // sqrt(128)

static __device__ __forceinline__ short f2bf(float f) {
    __hip_bfloat16 h = __float2bfloat16(f);
    union { __hip_bfloat16 h; short s; } u; u.h = h; return u.s;
}
static __device__ __forceinline__ float bf2f(short s) {
    union { __hip_bfloat16 h; short s; } u; u.s = s;
    return __bfloat162float(u.h);
}

// Pack 8 consecutive fp32 -> bf16x8 fragment
static __device__ __forceinline__ short8 load_cvt8(const float* __restrict__ p) {
    float4 a = *(const float4*)p;
    float4 b = *(const float4*)(p + 4);
    short8 o;
    o[0] = f2bf(a.x); o[1] = f2bf(a.y); o[2] = f2bf(a.z); o[3] = f2bf(a.w);
    o[4] = f2bf(b.x); o[5] = f2bf(b.y); o[6] = f2bf(b.z); o[7] = f2bf(b.w);
    return o;
}

// Fragment-major offset for qn/kn: matrix row g (0..4095), k index kidx (0..127)
// layout: [g>>4][kidx>>5][(kidx>>3)&3 * 16 + (g&15)][kidx&7]
// => a wave's MFMA fragment load (lane = quad*16+m, 8 bf16) is 64 consecutive
//    16 B chunks = one fully-coalesced 1 KB load.
static __device__ __forceinline__ int frag_off(int g, int kidx) {
    return ((((g >> 4) * 4 + (kidx >> 5)) * 4 + ((kidx >> 3) & 3)) * 16
            + (g & 15)) * 8 + (kidx & 7);
}

// ---------------- projection + metric-normalize (MFMA, bf16) ----------------
// 256 blocks: 32 rows x 128 cols each. 4 waves, each 32x32.
// Outputs qn/kn in fragment-major layout (see frag_off).
__global__ __launch_bounds__(256) void proj_kernel(
    const float* __restrict__ qp, const float* __restrict__ kp,
    const float* __restrict__ Wq, const float* __restrict__ bq,
    const float* __restrict__ Wk, const float* __restrict__ bk,
    __hip_bfloat16* __restrict__ qn, __hip_bfloat16* __restrict__ kn,
    float* __restrict__ rq, float* __restrict__ rk)
{
    int t = threadIdx.x;
    int b = blockIdx.x;                 // 0..255; 128 per matrix

    int which = b >> 7;
    int row0 = (b & 127) * 32;
    const float* x    = which ? kp : qp;
    const float* W    = which ? Wk : Wq;
    const float* bias = which ? bk : bq;
    short* outv = which ? (short*)kn : (short*)qn;
    float* outr = which ? rk : rq;

    int lane = t & 63, wid = t >> 6;
    int m = lane & 15, quad = lane >> 4;
    int colb = wid * 32;                // wave col origin (4 waves x 32 cols)

    floatx4 acc[2][2];
    #pragma unroll
    for (int i = 0; i < 2; ++i)
        #pragma unroll
        for (int j = 0; j < 2; ++j)
            acc[i][j] = (floatx4){0.f, 0.f, 0.f, 0.f};

    #pragma unroll
    for (int ks = 0; ks < 4; ++ks) {
        int koff = ks * 32 + quad * 8;
        short8 af[2], bfr[2];
        #pragma unroll
        for (int rt = 0; rt < 2; ++rt)
            af[rt] = load_cvt8(x + (row0 + rt*16 + m) * DD + koff);
        #pragma unroll
        for (int ct = 0; ct < 2; ++ct)
            bfr[ct] = load_cvt8(W + (colb + ct*16 + m) * DD + koff);
        #pragma unroll
        for (int rt = 0; rt < 2; ++rt)
            #pragma unroll
            for (int ct = 0; ct < 2; ++ct)
                acc[rt][ct] = __builtin_amdgcn_mfma_f32_16x16x32_bf16(
                    af[rt], bfr[ct], acc[rt][ct], 0, 0, 0);
    }

    __shared__ float buf[4][32];
    __shared__ float nfb[32];

    float bv[2];
    #pragma unroll
    for (int ct = 0; ct < 2; ++ct) bv[ct] = bias[colb + ct*16 + m];

    // add bias; per-row sum of squares (this wave's 32 cols), reduce over m
    #pragma unroll
    for (int rt = 0; rt < 2; ++rt) {
        #pragma unroll
        for (int r = 0; r < 4; ++r) {
            float p = 0.0f;
            #pragma unroll
            for (int ct = 0; ct < 2; ++ct) {
                float v = acc[rt][ct][r] + bv[ct];
                acc[rt][ct][r] = v;
                p = fmaf(v, v, p);
            }
            p += __shfl_xor(p, 1); p += __shfl_xor(p, 2);
            p += __shfl_xor(p, 4); p += __shfl_xor(p, 8);
            if (m == 0) buf[wid][rt*16 + quad*4 + r] = p;
        }
    }
    __syncthreads();
    if (t < 32) {
        float s = buf[0][t] + buf[1][t] + buf[2][t] + buf[3][t];
        float fro = sqrtf(s*s*(1.0f/16384.0f) + s*(1.0f/64.0f) + 128.0f);
        float qnorm = sqrtf((s*s*(1.0f/128.0f) + s) / (fro + EPSF));
        nfb[t] = 1.0f / (qnorm + EPSF);
    }
    __syncthreads();

    // scale, round to bf16, store (fragment-major); row-sum of rounded squares
    #pragma unroll
    for (int rt = 0; rt < 2; ++rt) {
        #pragma unroll
        for (int r = 0; r < 4; ++r) {
            int lrow = rt*16 + quad*4 + r;      // block-local 0..31
            int g = row0 + lrow;                // global matrix row
            float nf = nfb[lrow];
            float u = 0.0f;
            #pragma unroll
            for (int ct = 0; ct < 2; ++ct) {
                float v = acc[rt][ct][r] * nf;
                short sb = f2bf(v);
                outv[frag_off(g, colb + ct*16 + m)] = sb;
                float vf = bf2f(sb);
                u = fmaf(vf, vf, u);
            }
            u += __shfl_xor(u, 1); u += __shfl_xor(u, 2);
            u += __shfl_xor(u, 4); u += __shfl_xor(u, 8);
            if (m == 0) buf[wid][lrow] = u;
        }
    }
    __syncthreads();
    if (t < 32)
        outr[row0 + t] = buf[0][t] + buf[1][t] + buf[2][t] + buf[3][t];
}

// ---------------- scores: block owns 16 FULL rows ---------------------------
// 256 blocks x 1024 threads (16 waves = 4/SIMD). Wave w owns cols
// [w*256, w*256+256): 4 tiles of 64 cols, e kept in regs (64 fp32/lane).
// All fragment loads are fully-coalesced 1 KB wave loads (fragment-major qn/kn).
// LDS-reduce row sums across 16 waves -> block-local normalize, single store.
__global__ __launch_bounds__(1024) void score_rows(
    const __hip_bfloat16* __restrict__ qn, const __hip_bfloat16* __restrict__ kn,
    const float* __restrict__ rq, const float* __restrict__ rk,
    float* __restrict__ P)
{
    int lane = threadIdx.x & 63;
    int wid  = threadIdx.x >> 6;        // 0..15
    int m    = lane & 15;
    int quad = lane >> 4;

    int rowblk = blockIdx.x;            // 16 rows per block
    int r0 = rowblk * 16;
    int cs = wid * 256;                 // wave's column strip

    const short* qs  = (const short*)qn;
    const short* kks = (const short*)kn;

    // A fragments: 16 rows x K=128 (coalesced 1 KB loads)
    short8 af[4];
    #pragma unroll
    for (int k4 = 0; k4 < 4; ++k4)
        af[k4] = *(const short8*)(qs + ((rowblk*4 + k4)*64 + lane)*8);

    float rqv[4];
    #pragma unroll
    for (int r = 0; r < 4; ++r) rqv[r] = rq[r0 + quad*4 + r];

    floatx4 acc[4][4];                  // e values: 16 rows x 256 cols / 64 lanes
    float rs[4] = {0.f, 0.f, 0.f, 0.f};

    #pragma unroll
    for (int it = 0; it < 4; ++it) {
        #pragma unroll
        for (int ct = 0; ct < 4; ++ct) {
            int colblk = (cs >> 4) + it*4 + ct;
            short8 bfr[4];
            #pragma unroll
            for (int k4 = 0; k4 < 4; ++k4)
                bfr[k4] = *(const short8*)(kks + ((colblk*4 + k4)*64 + lane)*8);
            floatx4 a = (floatx4){0.f, 0.f, 0.f, 0.f};
            #pragma unroll
            for (int k4 = 0; k4 < 4; ++k4)
                a = __builtin_amdgcn_mfma_f32_16x16x32_bf16(af[k4], bfr[k4], a, 0, 0, 0);
            float rkv = rk[colblk*16 + m];
            #pragma unroll
            for (int r = 0; r < 4; ++r) {
                float d2 = fmaf(-2.0f, a[r], rqv[r] + rkv);
                float d  = d2 > 0.0f ? __builtin_amdgcn_sqrtf(d2) : 0.0f;
                float e  = __expf(TEMP * __builtin_amdgcn_rcpf(1.0f + d));
                a[r] = e;
                rs[r] += e;
            }
            acc[it][ct] = a;
        }
    }

    // reduce row sums over the 16 m-lanes
    #pragma unroll
    for (int r = 0; r < 4; ++r) {
        rs[r] += __shfl_xor(rs[r], 1); rs[r] += __shfl_xor(rs[r], 2);
        rs[r] += __shfl_xor(rs[r], 4); rs[r] += __shfl_xor(rs[r], 8);
    }

    __shared__ float sums[16][16];
    __shared__ float inv[16];
    if (m == 0) {
        #pragma unroll
        for (int r = 0; r < 4; ++r) sums[wid][quad*4 + r] = rs[r];
    }
    __syncthreads();
    if (threadIdx.x < 16) {
        float s = 0.f;
        #pragma unroll
        for (int w = 0; w < 16; ++w) s += sums[w][threadIdx.x];
        inv[threadIdx.x] = __builtin_amdgcn_rcpf(s + EPSF);
    }
    __syncthreads();

    float invv[4];
    #pragma unroll
    for (int r = 0; r < 4; ++r) invv[r] = inv[quad*4 + r];

    // single normalized store; each row's addresses ascend sequentially
    #pragma unroll
    for (int it = 0; it < 4; ++it) {
        #pragma unroll
        for (int ct = 0; ct < 4; ++ct) {
            #pragma unroll
            for (int r = 0; r < 4; ++r) {
                long row = r0 + quad*4 + r;
                P[row * NB + cs + it*64 + ct*16 + m] = acc[it][ct][r] * invv[r];
            }
        }
    }
}

extern "C" void kernel_launch(void* const* d_in, const int* in_sizes, int n_in,
                              void* d_out, int out_size, void* d_ws, size_t ws_size,
                              hipStream_t stream) {
    const float* qp = (const float*)d_in[0];
    const float* kp = (const float*)d_in[1];
    const float* Wq = (const float*)d_in[2];
    const float* bq = (const float*)d_in[3];
    const float* Wk = (const float*)d_in[4];
    const float* bk = (const float*)d_in[5];
    float* P = (float*)d_out;

    char* ws = (char*)d_ws;
    __hip_bfloat16* qn = (__hip_bfloat16*)ws;                         // 1 MB
    __hip_bfloat16* kn = (__hip_bfloat16*)(ws + (size_t)NB*DD*2);     // 1 MB
    float* rq = (float*)(ws + (size_t)NB*DD*4);                       // 16 KB
    float* rk = (float*)(ws + (size_t)NB*DD*4 + (size_t)NB*4);        // 16 KB

    hipLaunchKernelGGL(proj_kernel, dim3(256), dim3(256), 0, stream,
                       qp, kp, Wq, bq, Wk, bk, qn, kn, rq, rk);
    hipLaunchKernelGGL(score_rows, dim3(256), dim3(1024), 0, stream,
                       qn, kn, rq, rk, P);
}